// Round 6
// baseline (178.523 us; speedup 1.0000x reference)
//
#include <hip/hip_runtime.h>
#include <math.h>

#define H 256
#define N2 32
#define Bsz 8
#define Lseq 4096
#define BH (Bsz*H)          // 2048 sequences
#define NCH 32              // chunks along L
#define LC (Lseq/NCH)       // 128 chunk length
#define HN (H*N2)           // 8192

// workspace layout (float slots):
//  S  : BH*NCH*N2*2 fp32    chunk states (k_state: local finals; k_prefix -> incoming)
//  yb : BH*Lseq bf16        post-GELU activations
//  Wb : 512*256 bf16        pre-converted W
//  Tb : H*128*128 bf16      Toeplitz conv matrix T[h][j][m] = k[h][j-m] (0 if j<m)
//  Eb : H*128*64 bf16       emission basis E[h][j][p]   (j-major, p-contig)
//  Vb : H*64*128 bf16       state basis  V[h][p][j]     (p-major, j-contig)
#define S_OFF  0
#define Y_OFF  (S_OFF + BH*NCH*N2*2)
#define WB_OFF (Y_OFF + (BH*Lseq/2))
#define TB_OFF (WB_OFF + (512*256/2))
#define EB_OFF (TB_OFF + (H*128*128/2))
#define VB_OFF (EB_OFF + (H*128*64/2))

typedef __attribute__((ext_vector_type(8))) short bf16x8;
typedef __attribute__((ext_vector_type(8))) unsigned short u16x8;
typedef __attribute__((ext_vector_type(4))) float f32x4;

__device__ __forceinline__ unsigned short f2bf(float x) {
  union { float f; unsigned int u; } v; v.f = x;
  unsigned int r = v.u + 0x7fffu + ((v.u >> 16) & 1u);  // round-to-nearest-even
  return (unsigned short)(r >> 16);
}
__device__ __forceinline__ unsigned int packbf(float lo, float hi) {
  return (unsigned int)f2bf(lo) | ((unsigned int)f2bf(hi) << 16);
}
__device__ __forceinline__ float bf2f(unsigned short b) {
  union { unsigned int u; float f; } v; v.u = ((unsigned int)b) << 16;
  return v.f;
}

// ---------------- K0: prep — W->bf16, Toeplitz Tb, bases Eb & Vb ----------------
// grid 256 (h), block 128 (j).
__global__ __launch_bounds__(128) void k_prep(const float* __restrict__ log_dt,
                                              const float* __restrict__ C,
                                              const float* __restrict__ lar,
                                              const float* __restrict__ aim,
                                              const float* __restrict__ W,
                                              unsigned short* __restrict__ Wb,
                                              unsigned short* __restrict__ Tb,
                                              unsigned short* __restrict__ Eb,
                                              unsigned short* __restrict__ Vb) {
  __shared__ unsigned short kbuf[128];
  int h = blockIdx.x;
  int j = threadIdx.x;                        // 0..127
  // ---- W fp32 -> bf16: one float4 per thread (256*128 = 32768 = all of W/4) ----
  {
    int i = h * 128 + j;
    float4 v = *(const float4*)&W[i * 4];
    uint2 p; p.x = packbf(v.x, v.y); p.y = packbf(v.z, v.w);
    *(uint2*)&Wb[i * 4] = p;
  }
  float dt = expf(log_dt[h]);
  float kacc = 0.f;
  unsigned short* Erow = Eb + (h * 128 + j) * 64;
  for (int n = 0; n < 32; n++) {
    int hn = (h << 5) + n;
    float Ar = -expf(lar[hn]), Ai = aim[hn];
    float dAr = Ar * dt, dAi = Ai * dt;
    float er = expf(dAr), sw, cw;
    sincosf(dAi, &sw, &cw);
    float wr = er * cw, wi = er * sw;
    float emr = wr - 1.f, emi = wi;
    float inv = 1.f / (Ar * Ar + Ai * Ai);
    float qr = (emr * Ar + emi * Ai) * inv;
    float qi = (emi * Ar - emr * Ai) * inv;
    float Cr = C[2 * hn], Ci = C[2 * hn + 1];
    float c2r = 2.f * (Cr * qr - Ci * qi);    // 2*Ct
    float c2i = 2.f * (Cr * qi + Ci * qr);
    // k[j] += Re(2Ct * w^j)
    float ej = expf(dAr * (float)j), sj, cj;
    sincosf(dAi * (float)j, &sj, &cj);
    kacc = fmaf(c2r, ej * cj, fmaf(-c2i, ej * sj, kacc));
    // E[j][2n] = Re(2Ct w^{j+1}), E[j][2n+1] = -Im(2Ct w^{j+1})
    float e1 = expf(dAr * (float)(j + 1)), s1, c1;
    sincosf(dAi * (float)(j + 1), &s1, &c1);
    float w1r = e1 * c1, w1i = e1 * s1;
    Erow[2 * n]     = f2bf(c2r * w1r - c2i * w1i);
    Erow[2 * n + 1] = f2bf(-(c2r * w1i + c2i * w1r));
    // V[2n][j] = Re(w^{127-j}), V[2n+1][j] = Im(w^{127-j})
    float ev = expf(dAr * (float)(127 - j)), sv, cv;
    sincosf(dAi * (float)(127 - j), &sv, &cv);
    Vb[(h * 64 + 2 * n) * 128 + j]     = f2bf(ev * cv);
    Vb[(h * 64 + 2 * n + 1) * 128 + j] = f2bf(ev * sv);
  }
  kbuf[j] = f2bf(kacc);
  __syncthreads();
  // Toeplitz row j: Tb[h][j][m] = kbuf[j-m] (j>=m) else 0; vector u16x8 stores
  unsigned short* Trow = Tb + (h * 128 + j) * 128;
#pragma unroll
  for (int s8 = 0; s8 < 16; s8++) {
    u16x8 v;
#pragma unroll
    for (int t = 0; t < 8; t++) {
      int m = s8 * 8 + t;
      v[t] = (j >= m) ? kbuf[j - m] : (unsigned short)0;
    }
    *(u16x8*)&Trow[s8 * 8] = v;
  }
}

// ---------------- K1: MFMA chunk states: S[b,h,c,n] = sum_j u[...j] w^{127-j} ----------------
// Grid (H,4). Block: 64 rows (b,c) x 128 K(j) A-tile vs 64 p B-tile; 4 waves x 16 rows.
__global__ __launch_bounds__(256) void k_state(const float* __restrict__ u,
                                               const unsigned short* __restrict__ Vb,
                                               float* __restrict__ S) {
  __shared__ unsigned short Ul[64][136];   // stride 272 B = 17*16: aligned b128 reads
  __shared__ unsigned short Bl[64][136];
  int h   = blockIdx.x;
  int mq  = blockIdx.y;
  int tid = threadIdx.x;
  int wv = tid >> 6, lane = tid & 63;
  int n16 = lane & 15, quad = lane >> 4;
  int m0 = wv * 16;
  f32x4 acc[4] = {};
  // stage A: 64 rows x 128 fp32 -> bf16 (2048 float4s)
#pragma unroll
  for (int i = 0; i < 8; i++) {
    int e = tid + i * 256;
    int r = e >> 5, c4 = e & 31;
    int b = mq * 2 + (r >> 5), c = r & 31;
    float4 v = *(const float4*)&u[((b * 256 + h) * 4096 + c * 128 + c4 * 4)];
    *(unsigned int*)&Ul[r][c4 * 4]     = packbf(v.x, v.y);
    *(unsigned int*)&Ul[r][c4 * 4 + 2] = packbf(v.z, v.w);
  }
  // stage B: Vb[h]: 64 p-rows x 128 (1024 ushort8s)
#pragma unroll
  for (int i = 0; i < 4; i++) {
    int e = tid + i * 256;
    int p = e >> 4, s8 = e & 15;
    *(u16x8*)&Bl[p][s8 * 8] = *(const u16x8*)&Vb[(h * 64 + p) * 128 + s8 * 8];
  }
  __syncthreads();
#pragma unroll
  for (int ks = 0; ks < 128; ks += 32) {
    int kc = ks + quad * 8;
    bf16x8 af = *(const bf16x8*)&Ul[m0 + n16][kc];
#pragma unroll
    for (int nt = 0; nt < 4; nt++) {
      bf16x8 bf = *(const bf16x8*)&Bl[nt * 16 + n16][kc];
      acc[nt] = __builtin_amdgcn_mfma_f32_16x16x32_bf16(af, bf, acc[nt], 0, 0, 0);
    }
  }
#pragma unroll
  for (int reg = 0; reg < 4; reg++) {
    int m = m0 + quad * 4 + reg;
    int b = mq * 2 + (m >> 5), c = m & 31;
#pragma unroll
    for (int nt = 0; nt < 4; nt++) {
      int p = nt * 16 + n16;
      S[((b * 256 + h) * 32 + c) * 64 + p] = acc[nt][reg];
    }
  }
}

// ---------------- K2: serial prefix over chunks (in place), wL computed inline ----------------
__global__ void k_prefix(const float* __restrict__ log_dt, const float* __restrict__ lar,
                         const float* __restrict__ aim, float* __restrict__ S) {
  int t = blockIdx.x * blockDim.x + threadIdx.x;  // t < BH*N2
  if (t >= BH * N2) return;
  int n = t & 31, bh = t >> 5;
  int h = bh & (H - 1);
  int hn = (h << 5) + n;
  float dt  = expf(log_dt[h]);
  float dAr = -expf(lar[hn]) * dt, dAi = aim[hn] * dt;
  float eL = expf(dAr * (float)LC), sL, cL;
  sincosf(dAi * (float)LC, &sL, &cL);
  float wLr = eL * cL, wLi = eL * sL;
  float fr = 0.f, fi = 0.f;
  for (int c = 0; c < NCH; c++) {
    int si = (((bh * NCH + c) << 5) + n) << 1;
    float sr = S[si], s1 = S[si + 1];
    S[si] = fr; S[si + 1] = fi;             // incoming state for chunk c
    float nr = fmaf(wLr, fr, fmaf(-wLi, fi, sr));
    float ni = fmaf(wLr, fi, fmaf(wLi, fr, s1));
    fr = nr; fi = ni;
  }
}

// ---------------- K3: MFMA emit v2: single K=192 pass ----------------
// Y[m][j] = sum_k [u | F][m][k] * [Tt | E][j][k] ; + D*u, GELU -> yb (bf16)
// Grid (H, 4). Block 256 = 4 waves x 16 rows. One __syncthreads total; 48 MFMAs/wave.
// Epilogue reads bf16 u from LDS (no global re-fetch).
__global__ __launch_bounds__(256) void k_emit(const float* __restrict__ u,
                                              const float* __restrict__ S,
                                              const unsigned short* __restrict__ Tb,
                                              const unsigned short* __restrict__ Eb,
                                              const float* __restrict__ Dp,
                                              unsigned short* __restrict__ yb) {
  __shared__ unsigned short Ul[64][200];    // [row][k]: k 0..127 = u (bf16), 128..191 = F
  __shared__ unsigned short Bl[128][200];   // [j][k]:   k 0..127 = Toeplitz, 128..191 = E
  int h   = blockIdx.x;
  int mq  = blockIdx.y;
  int tid = threadIdx.x;
  int wv = tid >> 6, lane = tid & 63;
  int n16 = lane & 15, quad = lane >> 4;
  int m0 = wv * 16;
  f32x4 acc[8] = {};                        // nt = j-tile 0..7

  // ---- stage A.u: 64 rows x 128 fp32 -> bf16 (2048 float4s) ----
#pragma unroll
  for (int i = 0; i < 8; i++) {
    int e = tid + i * 256;
    int r = e >> 5, c4 = e & 31;
    int b = mq * 2 + (r >> 5), c = r & 31;
    float4 v = *(const float4*)&u[((b * 256 + h) * 4096 + c * 128 + c4 * 4)];
    *(unsigned int*)&Ul[r][c4 * 4]     = packbf(v.x, v.y);
    *(unsigned int*)&Ul[r][c4 * 4 + 2] = packbf(v.z, v.w);
  }
  // ---- stage A.F: 64 rows x 64 fp32 -> bf16 (1024 float4s) ----
#pragma unroll
  for (int i = 0; i < 4; i++) {
    int e = tid + i * 256;
    int r = e >> 4, c4 = e & 15;
    int b = mq * 2 + (r >> 5), c = r & 31;
    float4 v = *(const float4*)&S[((b * 256 + h) * 32 + c) * 64 + c4 * 4];
    *(unsigned int*)&Ul[r][128 + c4 * 4]     = packbf(v.x, v.y);
    *(unsigned int*)&Ul[r][128 + c4 * 4 + 2] = packbf(v.z, v.w);
  }
  // ---- stage B.T: 128 x 128 bf16 (2048 ushort8s) ----
#pragma unroll
  for (int i = 0; i < 8; i++) {
    int e = tid + i * 256;
    int jj = e >> 4, s8 = e & 15;
    *(u16x8*)&Bl[jj][s8 * 8] = *(const u16x8*)&Tb[(h * 128 + jj) * 128 + s8 * 8];
  }
  // ---- stage B.E: 128 x 64 bf16 (1024 ushort8s) ----
#pragma unroll
  for (int i = 0; i < 4; i++) {
    int e = tid + i * 256;
    int jj = e >> 3, p8 = e & 7;
    *(u16x8*)&Bl[jj][128 + p8 * 8] = *(const u16x8*)&Eb[(h * 128 + jj) * 64 + p8 * 8];
  }
  __syncthreads();
  // ---- 6 K-steps x 8 j-tiles, no barriers ----
#pragma unroll
  for (int ks = 0; ks < 192; ks += 32) {
    int kc = ks + quad * 8;
    bf16x8 af = *(const bf16x8*)&Ul[m0 + n16][kc];
#pragma unroll
    for (int nt = 0; nt < 8; nt++) {
      bf16x8 bf = *(const bf16x8*)&Bl[nt * 16 + n16][kc];
      acc[nt] = __builtin_amdgcn_mfma_f32_16x16x32_bf16(af, bf, acc[nt], 0, 0, 0);
    }
  }
  // ---- epilogue: + D*u (bf16 u from LDS), exact GELU, bf16 store ----
  float Dh = Dp[h];
#pragma unroll
  for (int reg = 0; reg < 4; reg++) {
    int m = m0 + quad * 4 + reg;
    int b = mq * 2 + (m >> 5), c = m & 31;
    int base = (b * 256 + h) * 4096 + c * 128;
#pragma unroll
    for (int nt = 0; nt < 8; nt++) {
      int j = nt * 16 + n16;
      float uv = bf2f(Ul[m][j]);
      float v  = fmaf(Dh, uv, acc[nt][reg]);
      float ge = 0.5f * v * (1.0f + erff(v * 0.70710678118654752f));
      yb[base + j] = f2bf(ge);
    }
  }
}

// ---------------- K4: MFMA bf16 GEMM: z = W@y + b ; out = a * sigmoid(g) ----------------
__global__ __launch_bounds__(256) void k_gemm(const unsigned short* __restrict__ yb,
                                              const unsigned short* __restrict__ Wb,
                                              const float* __restrict__ bias,
                                              float* __restrict__ out) {
  __shared__ unsigned short Ws[128][72];
  __shared__ unsigned short Ys[128][72];
  int tid  = threadIdx.x;
  int l0   = blockIdx.x * 128;
  int o0   = blockIdx.y * 64;
  int bb   = blockIdx.z;
  int wave = tid >> 6;
  int lane = tid & 63;
  int wo   = wave & 1;
  int wl   = wave >> 1;
  int n    = lane & 15;
  int quad = lane >> 4;

  f32x4 acc_a[2][4] = {};
  f32x4 acc_g[2][4] = {};

  for (int kk = 0; kk < H; kk += 64) {
#pragma unroll
    for (int i = 0; i < 4; i++) {
      int e = tid + i * 256;
      int r = e >> 3, s = e & 7;
      int gr = (r < 64) ? (o0 + r) : (192 + o0 + r);
      *(u16x8*)&Ws[r][s * 8] = *(const u16x8*)&Wb[gr * 256 + kk + s * 8];
    }
    {
      int kcol = tid & 63;
      int lg0  = tid >> 6;
      const unsigned short* yrow = yb + (bb * 256 + kk + kcol) * 4096 + l0;
#pragma unroll
      for (int i = 0; i < 4; i++) {
        int l8 = (lg0 * 4 + i) * 8;
        u16x8 v = *(const u16x8*)&yrow[l8];
#pragma unroll
        for (int jj = 0; jj < 8; jj++)
          Ys[l8 + jj][kcol] = v[jj];
      }
    }
    __syncthreads();
#pragma unroll
    for (int ks = 0; ks < 64; ks += 32) {
      int kc = ks + quad * 8;
      bf16x8 af_a[2], af_g[2], bfr[4];
#pragma unroll
      for (int mt = 0; mt < 2; mt++) {
        af_a[mt] = *(const bf16x8*)&Ws[wo * 32 + mt * 16 + n][kc];
        af_g[mt] = *(const bf16x8*)&Ws[64 + wo * 32 + mt * 16 + n][kc];
      }
#pragma unroll
      for (int lt = 0; lt < 4; lt++)
        bfr[lt] = *(const bf16x8*)&Ys[wl * 64 + lt * 16 + n][kc];
#pragma unroll
      for (int mt = 0; mt < 2; mt++)
#pragma unroll
        for (int lt = 0; lt < 4; lt++) {
          acc_a[mt][lt] = __builtin_amdgcn_mfma_f32_16x16x32_bf16(af_a[mt], bfr[lt], acc_a[mt][lt], 0, 0, 0);
          acc_g[mt][lt] = __builtin_amdgcn_mfma_f32_16x16x32_bf16(af_g[mt], bfr[lt], acc_g[mt][lt], 0, 0, 0);
        }
    }
    __syncthreads();
  }
#pragma unroll
  for (int mt = 0; mt < 2; mt++) {
    int ob = o0 + wo * 32 + mt * 16 + quad * 4;
#pragma unroll
    for (int reg = 0; reg < 4; reg++) {
      int op = ob + reg;
      float ba = bias[op], bg = bias[H + op];
      float* orow = &out[(bb * H + op) * Lseq + l0 + wl * 64 + n];
#pragma unroll
      for (int lt = 0; lt < 4; lt++) {
        float a = acc_a[mt][lt][reg] + ba;
        float g = acc_g[mt][lt][reg] + bg;
        orow[lt * 16] = a / (1.0f + expf(-g));
      }
    }
  }
}

extern "C" void kernel_launch(void* const* d_in, const int* in_sizes, int n_in,
                              void* d_out, int out_size, void* d_ws, size_t ws_size,
                              hipStream_t stream) {
  const float* u      = (const float*)d_in[0];
  const float* log_dt = (const float*)d_in[1];
  const float* C      = (const float*)d_in[2];
  const float* lar    = (const float*)d_in[3];
  const float* aim    = (const float*)d_in[4];
  const float* Dp     = (const float*)d_in[5];
  const float* W      = (const float*)d_in[6];
  const float* bias   = (const float*)d_in[7];
  float* out = (float*)d_out;
  float* ws  = (float*)d_ws;
  float* S   = ws + S_OFF;
  unsigned short* yb  = (unsigned short*)(ws + Y_OFF);
  unsigned short* Wb  = (unsigned short*)(ws + WB_OFF);
  unsigned short* Tbg = (unsigned short*)(ws + TB_OFF);
  unsigned short* Ebg = (unsigned short*)(ws + EB_OFF);
  unsigned short* Vbg = (unsigned short*)(ws + VB_OFF);

  hipLaunchKernelGGL(k_prep,   dim3(H), dim3(128), 0, stream, log_dt, C, lar, aim, W, Wb, Tbg, Ebg, Vbg);
  hipLaunchKernelGGL(k_state,  dim3(H, 4), dim3(256), 0, stream, u, Vbg, S);
  hipLaunchKernelGGL(k_prefix, dim3(BH * N2 / 256), dim3(256), 0, stream, log_dt, lar, aim, S);
  hipLaunchKernelGGL(k_emit,   dim3(H, 4), dim3(256), 0, stream, u, S, Tbg, Ebg, Dp, yb);
  hipLaunchKernelGGL(k_gemm,   dim3(Lseq / 128, H / 64, Bsz), dim3(256), 0, stream, yb, Wb, bias, out);
}

// Round 7
// 167.328 us; speedup vs baseline: 1.0669x; 1.0669x over previous
//
#include <hip/hip_runtime.h>
#include <math.h>

#define H 256
#define N2 32
#define Bsz 8
#define Lseq 4096
#define BH (Bsz*H)          // 2048 sequences
#define NCH 32              // chunks along L
#define LC (Lseq/NCH)       // 128 chunk length
#define HN (H*N2)           // 8192

// workspace layout (float slots):
//  yb : BH*Lseq bf16        post-GELU activations
//  Wb : 512*256 bf16        pre-converted W
//  Tb : H*128*128 bf16      Toeplitz conv matrix T[h][j][m] = k[h][j-m] (0 if j<m)
//  Eb : H*128*64 bf16       emission basis E[h][j][p]   (j-major, p-contig)
//  Vb : H*64*128 bf16       state basis  V[h][p][j]     (p-major, j-contig)
#define Y_OFF  0
#define WB_OFF (Y_OFF + (BH*Lseq/2))
#define TB_OFF (WB_OFF + (512*256/2))
#define EB_OFF (TB_OFF + (H*128*128/2))
#define VB_OFF (EB_OFF + (H*128*64/2))

typedef __attribute__((ext_vector_type(8))) short bf16x8;
typedef __attribute__((ext_vector_type(8))) unsigned short u16x8;
typedef __attribute__((ext_vector_type(4))) float f32x4;

__device__ __forceinline__ unsigned short f2bf(float x) {
  union { float f; unsigned int u; } v; v.f = x;
  unsigned int r = v.u + 0x7fffu + ((v.u >> 16) & 1u);  // round-to-nearest-even
  return (unsigned short)(r >> 16);
}
__device__ __forceinline__ unsigned int packbf(float lo, float hi) {
  return (unsigned int)f2bf(lo) | ((unsigned int)f2bf(hi) << 16);
}
__device__ __forceinline__ float bf2f(unsigned short b) {
  union { unsigned int u; float f; } v; v.u = ((unsigned int)b) << 16;
  return v.f;
}

// ---------------- K0: prep — W->bf16, Toeplitz Tb, bases Eb & Vb ----------------
// grid 256 (h), block 128 (j).
__global__ __launch_bounds__(128) void k_prep(const float* __restrict__ log_dt,
                                              const float* __restrict__ C,
                                              const float* __restrict__ lar,
                                              const float* __restrict__ aim,
                                              const float* __restrict__ W,
                                              unsigned short* __restrict__ Wb,
                                              unsigned short* __restrict__ Tb,
                                              unsigned short* __restrict__ Eb,
                                              unsigned short* __restrict__ Vb) {
  __shared__ unsigned short kbuf[128];
  int h = blockIdx.x;
  int j = threadIdx.x;                        // 0..127
  // ---- W fp32 -> bf16: one float4 per thread (256*128 = 32768 = all of W/4) ----
  {
    int i = h * 128 + j;
    float4 v = *(const float4*)&W[i * 4];
    uint2 p; p.x = packbf(v.x, v.y); p.y = packbf(v.z, v.w);
    *(uint2*)&Wb[i * 4] = p;
  }
  float dt = expf(log_dt[h]);
  float kacc = 0.f;
  unsigned short* Erow = Eb + (h * 128 + j) * 64;
  for (int n = 0; n < 32; n++) {
    int hn = (h << 5) + n;
    float Ar = -expf(lar[hn]), Ai = aim[hn];
    float dAr = Ar * dt, dAi = Ai * dt;
    float er = expf(dAr), sw, cw;
    sincosf(dAi, &sw, &cw);
    float wr = er * cw, wi = er * sw;
    float emr = wr - 1.f, emi = wi;
    float inv = 1.f / (Ar * Ar + Ai * Ai);
    float qr = (emr * Ar + emi * Ai) * inv;
    float qi = (emi * Ar - emr * Ai) * inv;
    float Cr = C[2 * hn], Ci = C[2 * hn + 1];
    float c2r = 2.f * (Cr * qr - Ci * qi);    // 2*Ct
    float c2i = 2.f * (Cr * qi + Ci * qr);
    // k[j] += Re(2Ct * w^j)
    float ej = expf(dAr * (float)j), sj, cj;
    sincosf(dAi * (float)j, &sj, &cj);
    kacc = fmaf(c2r, ej * cj, fmaf(-c2i, ej * sj, kacc));
    // E[j][2n] = Re(2Ct w^{j+1}), E[j][2n+1] = -Im(2Ct w^{j+1})
    float e1 = expf(dAr * (float)(j + 1)), s1, c1;
    sincosf(dAi * (float)(j + 1), &s1, &c1);
    float w1r = e1 * c1, w1i = e1 * s1;
    Erow[2 * n]     = f2bf(c2r * w1r - c2i * w1i);
    Erow[2 * n + 1] = f2bf(-(c2r * w1i + c2i * w1r));
    // V[2n][j] = Re(w^{127-j}), V[2n+1][j] = Im(w^{127-j})
    float ev = expf(dAr * (float)(127 - j)), sv, cv;
    sincosf(dAi * (float)(127 - j), &sv, &cv);
    Vb[(h * 64 + 2 * n) * 128 + j]     = f2bf(ev * cv);
    Vb[(h * 64 + 2 * n + 1) * 128 + j] = f2bf(ev * sv);
  }
  kbuf[j] = f2bf(kacc);
  __syncthreads();
  // Toeplitz row j: Tb[h][j][m] = kbuf[j-m] (j>=m) else 0; vector u16x8 stores
  unsigned short* Trow = Tb + (h * 128 + j) * 128;
#pragma unroll
  for (int s8 = 0; s8 < 16; s8++) {
    u16x8 v;
#pragma unroll
    for (int t = 0; t < 8; t++) {
      int m = s8 * 8 + t;
      v[t] = (j >= m) ? kbuf[j - m] : (unsigned short)0;
    }
    *(u16x8*)&Trow[s8 * 8] = v;
  }
}

// ---------------- K1: fused SSM: states + prefix + emit, one block per (b,h) ----------------
// Block = 256 thr = 4 waves. Phases:
//  1. stage u (fp32->bf16) into Ub[32][136]  (c=chunk, j=pos-in-chunk)
//  2. state GEMM  S[c][p] = sum_j Ub[c][j] * Vb[h][p][j]   (B direct from global, L2-hot)
//     -> Fb (fp32 LDS)
//  3. wave0: serial prefix over c per complex pair n -> incoming states -> Fl (bf16 LDS)
//  4. emit GEMM   Y[c][j] = sum_k [Ub|Fl][c][k] * [Tb|Eb][h][j][k]  (K=192, B from global)
//  5. epilogue: v = D*u + Y, exact GELU, store yb (bf16)
__global__ __launch_bounds__(256) void k_ssm(const float* __restrict__ u,
                                             const float* __restrict__ log_dt,
                                             const float* __restrict__ lar,
                                             const float* __restrict__ aim,
                                             const unsigned short* __restrict__ Vb,
                                             const unsigned short* __restrict__ Tb,
                                             const unsigned short* __restrict__ Eb,
                                             const float* __restrict__ Dp,
                                             unsigned short* __restrict__ yb) {
  __shared__ unsigned short Ub[32][136];   // row stride 272 B (17*16): aligned b128
  __shared__ float          Fb[32][68];    // chunk-final states (fp32)
  __shared__ unsigned short Fl[32][72];    // incoming states (bf16), row stride 144 B
  int g   = blockIdx.x;
  int b   = g & 7, h = g >> 3;             // same-h blocks adjacent -> T/E/V L2 locality
  int tid = threadIdx.x;
  int wv = tid >> 6, lane = tid & 63;
  int n16 = lane & 15, quad = lane >> 4;
  const float* ubase = u + (b * 256 + h) * 4096;

  // ---- phase 1: stage u ----
#pragma unroll
  for (int i = 0; i < 2; i++) {
    int idx = tid * 2 + i;                  // 0..511 float8s
    float4 va = *(const float4*)(ubase + idx * 8);
    float4 vb4 = *(const float4*)(ubase + idx * 8 + 4);
    unsigned short* dst = &Ub[idx >> 4][(idx & 15) * 8];
    *(unsigned int*)(dst)     = packbf(va.x, va.y);
    *(unsigned int*)(dst + 2) = packbf(va.z, va.w);
    *(unsigned int*)(dst + 4) = packbf(vb4.x, vb4.y);
    *(unsigned int*)(dst + 6) = packbf(vb4.z, vb4.w);
  }
  __syncthreads();

  // ---- phase 2: state GEMM (M=32 c, N=64 p, K=128 j); wave wv owns p-tile wv ----
  {
    f32x4 sacc[2] = {};
#pragma unroll
    for (int ks = 0; ks < 128; ks += 32) {
      int kc = ks + quad * 8;
      bf16x8 bv = *(const bf16x8*)&Vb[(h * 64 + wv * 16 + n16) * 128 + kc];
#pragma unroll
      for (int mt = 0; mt < 2; mt++) {
        bf16x8 av = *(const bf16x8*)&Ub[mt * 16 + n16][kc];
        sacc[mt] = __builtin_amdgcn_mfma_f32_16x16x32_bf16(av, bv, sacc[mt], 0, 0, 0);
      }
    }
#pragma unroll
    for (int mt = 0; mt < 2; mt++)
#pragma unroll
      for (int reg = 0; reg < 4; reg++)
        Fb[mt * 16 + quad * 4 + reg][wv * 16 + n16] = sacc[mt][reg];
  }
  __syncthreads();

  // ---- phase 3: serial prefix (wave 0, lane n = complex pair) ----
  if (wv == 0 && lane < 32) {
    int n = lane, hn = (h << 5) + n;
    float dt  = expf(log_dt[h]);
    float dAr = -expf(lar[hn]) * dt, dAi = aim[hn] * dt;
    float eL = expf(dAr * (float)LC), sL, cL;
    sincosf(dAi * (float)LC, &sL, &cL);
    float wLr = eL * cL, wLi = eL * sL;
    float fr = 0.f, fi = 0.f;
    for (int c = 0; c < NCH; c++) {
      float sr = Fb[c][2 * n], si = Fb[c][2 * n + 1];
      *(unsigned int*)&Fl[c][2 * n] = packbf(fr, fi);   // incoming state for chunk c
      float nr = fmaf(wLr, fr, fmaf(-wLi, fi, sr));
      float ni = fmaf(wLr, fi, fmaf(wLi, fr, si));
      fr = nr; fi = ni;
    }
  }
  __syncthreads();

  // ---- phase 4: emit GEMM (M=32 c, N=128 j, K=192 [u|F]); wave wv owns j-tiles 2wv,2wv+1 ----
  f32x4 acc[2][2] = {};                     // [mt][ntl]
#pragma unroll
  for (int ks = 0; ks < 192; ks += 32) {
    int kc = ks + quad * 8;
    bf16x8 av[2];
#pragma unroll
    for (int mt = 0; mt < 2; mt++)
      av[mt] = (ks < 128) ? *(const bf16x8*)&Ub[mt * 16 + n16][kc]
                          : *(const bf16x8*)&Fl[mt * 16 + n16][kc - 128];
#pragma unroll
    for (int ntl = 0; ntl < 2; ntl++) {
      int j = (wv * 2 + ntl) * 16 + n16;
      bf16x8 bv = (ks < 128) ? *(const bf16x8*)&Tb[(h * 128 + j) * 128 + kc]
                             : *(const bf16x8*)&Eb[(h * 128 + j) * 64 + kc - 128];
#pragma unroll
      for (int mt = 0; mt < 2; mt++)
        acc[mt][ntl] = __builtin_amdgcn_mfma_f32_16x16x32_bf16(av[mt], bv, acc[mt][ntl], 0, 0, 0);
    }
  }

  // ---- phase 5: epilogue ----
  float Dh = Dp[h];
  unsigned short* ybase = yb + (b * 256 + h) * 4096;
#pragma unroll
  for (int mt = 0; mt < 2; mt++) {
#pragma unroll
    for (int reg = 0; reg < 4; reg++) {
      int c = mt * 16 + quad * 4 + reg;
#pragma unroll
      for (int ntl = 0; ntl < 2; ntl++) {
        int j = (wv * 2 + ntl) * 16 + n16;
        float uv = bf2f(Ub[c][j]);
        float v  = fmaf(Dh, uv, acc[mt][ntl][reg]);
        float ge = 0.5f * v * (1.0f + erff(v * 0.70710678118654752f));
        ybase[c * 128 + j] = f2bf(ge);
      }
    }
  }
}

// ---------------- K4: MFMA bf16 GEMM: z = W@y + b ; out = a * sigmoid(g) ----------------
__global__ __launch_bounds__(256) void k_gemm(const unsigned short* __restrict__ yb,
                                              const unsigned short* __restrict__ Wb,
                                              const float* __restrict__ bias,
                                              float* __restrict__ out) {
  __shared__ unsigned short Ws[128][72];
  __shared__ unsigned short Ys[128][72];
  int tid  = threadIdx.x;
  int l0   = blockIdx.x * 128;
  int o0   = blockIdx.y * 64;
  int bb   = blockIdx.z;
  int wave = tid >> 6;
  int lane = tid & 63;
  int wo   = wave & 1;
  int wl   = wave >> 1;
  int n    = lane & 15;
  int quad = lane >> 4;

  f32x4 acc_a[2][4] = {};
  f32x4 acc_g[2][4] = {};

  for (int kk = 0; kk < H; kk += 64) {
#pragma unroll
    for (int i = 0; i < 4; i++) {
      int e = tid + i * 256;
      int r = e >> 3, s = e & 7;
      int gr = (r < 64) ? (o0 + r) : (192 + o0 + r);
      *(u16x8*)&Ws[r][s * 8] = *(const u16x8*)&Wb[gr * 256 + kk + s * 8];
    }
    {
      int kcol = tid & 63;
      int lg0  = tid >> 6;
      const unsigned short* yrow = yb + (bb * 256 + kk + kcol) * 4096 + l0;
#pragma unroll
      for (int i = 0; i < 4; i++) {
        int l8 = (lg0 * 4 + i) * 8;
        u16x8 v = *(const u16x8*)&yrow[l8];
#pragma unroll
        for (int jj = 0; jj < 8; jj++)
          Ys[l8 + jj][kcol] = v[jj];
      }
    }
    __syncthreads();
#pragma unroll
    for (int ks = 0; ks < 64; ks += 32) {
      int kc = ks + quad * 8;
      bf16x8 af_a[2], af_g[2], bfr[4];
#pragma unroll
      for (int mt = 0; mt < 2; mt++) {
        af_a[mt] = *(const bf16x8*)&Ws[wo * 32 + mt * 16 + n][kc];
        af_g[mt] = *(const bf16x8*)&Ws[64 + wo * 32 + mt * 16 + n][kc];
      }
#pragma unroll
      for (int lt = 0; lt < 4; lt++)
        bfr[lt] = *(const bf16x8*)&Ys[wl * 64 + lt * 16 + n][kc];
#pragma unroll
      for (int mt = 0; mt < 2; mt++)
#pragma unroll
        for (int lt = 0; lt < 4; lt++) {
          acc_a[mt][lt] = __builtin_amdgcn_mfma_f32_16x16x32_bf16(af_a[mt], bfr[lt], acc_a[mt][lt], 0, 0, 0);
          acc_g[mt][lt] = __builtin_amdgcn_mfma_f32_16x16x32_bf16(af_g[mt], bfr[lt], acc_g[mt][lt], 0, 0, 0);
        }
    }
    __syncthreads();
  }
#pragma unroll
  for (int mt = 0; mt < 2; mt++) {
    int ob = o0 + wo * 32 + mt * 16 + quad * 4;
#pragma unroll
    for (int reg = 0; reg < 4; reg++) {
      int op = ob + reg;
      float ba = bias[op], bg = bias[H + op];
      float* orow = &out[(bb * H + op) * Lseq + l0 + wl * 64 + n];
#pragma unroll
      for (int lt = 0; lt < 4; lt++) {
        float a = acc_a[mt][lt][reg] + ba;
        float g = acc_g[mt][lt][reg] + bg;
        orow[lt * 16] = a / (1.0f + expf(-g));
      }
    }
  }
}

extern "C" void kernel_launch(void* const* d_in, const int* in_sizes, int n_in,
                              void* d_out, int out_size, void* d_ws, size_t ws_size,
                              hipStream_t stream) {
  const float* u      = (const float*)d_in[0];
  const float* log_dt = (const float*)d_in[1];
  const float* C      = (const float*)d_in[2];
  const float* lar    = (const float*)d_in[3];
  const float* aim    = (const float*)d_in[4];
  const float* Dp     = (const float*)d_in[5];
  const float* W      = (const float*)d_in[6];
  const float* bias   = (const float*)d_in[7];
  float* out = (float*)d_out;
  float* ws  = (float*)d_ws;
  unsigned short* yb  = (unsigned short*)(ws + Y_OFF);
  unsigned short* Wb  = (unsigned short*)(ws + WB_OFF);
  unsigned short* Tbg = (unsigned short*)(ws + TB_OFF);
  unsigned short* Ebg = (unsigned short*)(ws + EB_OFF);
  unsigned short* Vbg = (unsigned short*)(ws + VB_OFF);

  hipLaunchKernelGGL(k_prep, dim3(H), dim3(128), 0, stream, log_dt, C, lar, aim, W, Wb, Tbg, Ebg, Vbg);
  hipLaunchKernelGGL(k_ssm,  dim3(BH), dim3(256), 0, stream, u, log_dt, lar, aim, Vbg, Tbg, Ebg, Dp, yb);
  hipLaunchKernelGGL(k_gemm, dim3(Lseq / 128, H / 64, Bsz), dim3(256), 0, stream, yb, Wb, bias, out);
}